// Round 3
// baseline (163.843 us; speedup 1.0000x reference)
//
#include <hip/hip_runtime.h>
#include <math.h>

// ConsistencyLoss: KL( softmax(soft/T) || softmax(logits/T) ) * T^2, batchmean.
// B = 4,194,304, C = 5, T = 3. Memory-bound streaming reduction (~100 MB read).
//
// R3: loop-free — exactly one quad (4 samples) per thread, 4096 blocks x 256
// -> max TLP for latency hiding. Transcendental trims: e_main via rcp(e_nb),
// single fused log. 8 quarter-rate ops/sample.

constexpr int   kC     = 5;
constexpr float kInvT  = 1.0f / 3.0f;
constexpr float kExp13 = 1.3956124250860895f;   // e^{1/3}
constexpr int   kBatch = 4194304;

__global__ void zero_out_kernel(float* out) {
    if (threadIdx.x == 0) out[0] = 0.0f;
}

__global__ __launch_bounds__(256) void kl_partial_kernel(
    const float* __restrict__ score,
    const float* __restrict__ logits,
    float* __restrict__ out) {

    const int q = blockIdx.x * blockDim.x + threadIdx.x;   // quad index, one per thread

    // 4 consecutive samples: score as one float4, logits rows as 5x float4
    // (4 rows * 5 classes = 20 floats; q*80 bytes is 16B-aligned).
    const float4 s4 = reinterpret_cast<const float4*>(score)[q];
    const float4* lrow = reinterpret_cast<const float4*>(logits + (size_t)q * 20);
    const float4 L0 = lrow[0], L1 = lrow[1], L2 = lrow[2], L3 = lrow[3], L4 = lrow[4];

    const float v[20] = {L0.x, L0.y, L0.z, L0.w,
                         L1.x, L1.y, L1.z, L1.w,
                         L2.x, L2.y, L2.z, L2.w,
                         L3.x, L3.y, L3.z, L3.w,
                         L4.x, L4.y, L4.z, L4.w};
    const float ss[4] = {s4.x, s4.y, s4.z, s4.w};

    float acc = 0.0f;
    #pragma unroll
    for (int r = 0; r < 4; ++r) {
        const float s  = ss[r];
        const float l0 = v[r * 5 + 0], l1 = v[r * 5 + 1], l2 = v[r * 5 + 2],
                    l3 = v[r * 5 + 3], l4 = v[r * 5 + 4];

        // --- soft target geometry (matches reference exactly) ---
        const float sc     = fminf(fmaxf(s * 5.0f, 0.0f), 4.0f);
        const int   idx    = (int)sc;                    // floor, s >= 0
        const float center = ((float)idx + 0.5f) * 0.2f;
        float       d      = fabsf(s - center) * 5.0f;
        const bool  lo     = (idx > 0) && (s < center);
        const bool  hi     = (idx < kC - 1) && (s > center);
        const bool  nb     = lo || hi;
        d = nb ? d : 0.0f;                               // unifies !nb case
        const int nbi = idx + (hi ? 1 : 0) - (lo ? 1 : 0);

        // Target-side: soft = {1-d at idx, d at nbi, 0 elsewhere}.
        // e_main = exp((1-d)/3) = e^{1/3} / exp(d/3)  -> one exp + one rcp
        const float e_nb   = __expf(d * kInvT);
        const float e_main = kExp13 * __builtin_amdgcn_rcpf(e_nb);

        // logits sum + indexed picks
        const float S = l0 + l1 + l2 + l3 + l4;
        const float l_main = (idx == 0) ? l0 : (idx == 1) ? l1 :
                             (idx == 2) ? l2 : (idx == 3) ? l3 : l4;
        const float l_nb   = (nbi == 0) ? l0 : (nbi == 1) ? l1 :
                             (nbi == 2) ? l2 : (nbi == 3) ? l3 : l4;

        // Zq: no max-subtraction needed, |l|/3 stays well in range
        const float Zq = __expf(l0 * kInvT) + __expf(l1 * kInvT) +
                         __expf(l2 * kInvT) + __expf(l3 * kInvT) +
                         __expf(l4 * kInvT);

        const float Zp  = e_main + e_nb + 3.0f;
        const float rZp = __builtin_amdgcn_rcpf(Zp);
        const float Spa = e_main * (1.0f - d) + e_nb * d;
        const float Spl = e_main * l_main + e_nb * l_nb + (S - l_main - l_nb);

        // kl_i = invT*(Spa-Spl)/Zp + ln(Zq/Zp)
        acc += kInvT * (Spa - Spl) * rZp + __logf(Zq * rZp);
    }

    // --- wave (64-lane) shuffle reduction ---
    #pragma unroll
    for (int off = 32; off > 0; off >>= 1) acc += __shfl_down(acc, off, 64);

    // --- cross-wave LDS reduction (256 threads = 4 waves) ---
    __shared__ float wsum[4];
    const int lane = threadIdx.x & 63;
    const int wave = threadIdx.x >> 6;
    if (lane == 0) wsum[wave] = acc;
    __syncthreads();
    if (threadIdx.x == 0) {
        const float b = wsum[0] + wsum[1] + wsum[2] + wsum[3];
        atomicAdd(out, b * (9.0f / (float)kBatch));   // * T^2 / B
    }
}

extern "C" void kernel_launch(void* const* d_in, const int* in_sizes, int n_in,
                              void* d_out, int out_size, void* d_ws, size_t ws_size,
                              hipStream_t stream) {
    const float* score  = (const float*)d_in[0];   // quality_score [B]
    const float* logits = (const float*)d_in[1];   // class_logits [B,5]
    float* out = (float*)d_out;

    const int B = in_sizes[0];         // 4,194,304
    const int nquads = B / 4;          // 1,048,576 -> 4096 blocks x 256 threads
    const int blocks = nquads / 256;

    zero_out_kernel<<<1, 64, 0, stream>>>(out);
    kl_partial_kernel<<<blocks, 256, 0, stream>>>(score, logits, out);
}

// Round 5
// 135.911 us; speedup vs baseline: 1.2055x; 1.2055x over previous
//
#include <hip/hip_runtime.h>
#include <math.h>

// ConsistencyLoss: KL( softmax(soft/T) || softmax(logits/T) ) * T^2, batchmean.
// B = 4,194,304, C = 5, T = 3.
//
// R5: same as R4 (LDS-staged coalescing; R3's direct 80-B-strided float4
// loads were transaction-rate bound at 800 GB/s), but the LDS tile is a
// native float4 array — R4 cast a __shared__ float[] (4 B aligned) to
// float4* (UB -> dispatch abort). float4 declaration guarantees 16 B
// alignment for ds_*_b128.

constexpr int   kC     = 5;
constexpr float kInvT  = 1.0f / 3.0f;
constexpr float kExp13 = 1.3956124250860895f;   // e^{1/3}
constexpr int   kBatch = 4194304;

constexpr int kThreads      = 256;
constexpr int kQuadsPerTile = 512;                         // 2048 samples / block
constexpr int kTileVec4     = kQuadsPerTile * 5;           // 2560 float4 = 40 KB
constexpr int kBlocks       = (kBatch / 4) / kQuadsPerTile; // 2048

__device__ __forceinline__ float kl_quad(float4 P0, float4 P1, float4 P2,
                                         float4 P3, float4 P4, float4 s4) {
    const float v[20] = {P0.x, P0.y, P0.z, P0.w,
                         P1.x, P1.y, P1.z, P1.w,
                         P2.x, P2.y, P2.z, P2.w,
                         P3.x, P3.y, P3.z, P3.w,
                         P4.x, P4.y, P4.z, P4.w};
    const float ss[4] = {s4.x, s4.y, s4.z, s4.w};

    float acc = 0.0f;
    #pragma unroll
    for (int r = 0; r < 4; ++r) {
        const float s  = ss[r];
        const float l0 = v[r * 5 + 0], l1 = v[r * 5 + 1], l2 = v[r * 5 + 2],
                    l3 = v[r * 5 + 3], l4 = v[r * 5 + 4];

        // --- soft target geometry (matches reference exactly) ---
        const float sc     = fminf(fmaxf(s * 5.0f, 0.0f), 4.0f);
        const int   idx    = (int)sc;                    // floor, s >= 0
        const float center = ((float)idx + 0.5f) * 0.2f;
        float       d      = fabsf(s - center) * 5.0f;
        const bool  lo     = (idx > 0) && (s < center);
        const bool  hi     = (idx < kC - 1) && (s > center);
        const bool  nb     = lo || hi;
        d = nb ? d : 0.0f;
        const int nbi = idx + (hi ? 1 : 0) - (lo ? 1 : 0);

        // soft = {1-d at idx, d at nbi, 0 elsewhere};  e_main = e^{1/3}/e_nb
        const float e_nb   = __expf(d * kInvT);
        const float e_main = kExp13 * __builtin_amdgcn_rcpf(e_nb);

        const float S = l0 + l1 + l2 + l3 + l4;
        const float l_main = (idx == 0) ? l0 : (idx == 1) ? l1 :
                             (idx == 2) ? l2 : (idx == 3) ? l3 : l4;
        const float l_nb   = (nbi == 0) ? l0 : (nbi == 1) ? l1 :
                             (nbi == 2) ? l2 : (nbi == 3) ? l3 : l4;

        const float Zq = __expf(l0 * kInvT) + __expf(l1 * kInvT) +
                         __expf(l2 * kInvT) + __expf(l3 * kInvT) +
                         __expf(l4 * kInvT);

        const float Zp  = e_main + e_nb + 3.0f;
        const float rZp = __builtin_amdgcn_rcpf(Zp);
        const float Spa = e_main * (1.0f - d) + e_nb * d;
        const float Spl = e_main * l_main + e_nb * l_nb + (S - l_main - l_nb);

        acc += kInvT * (Spa - Spl) * rZp + __logf(Zq * rZp);
    }
    return acc;
}

__global__ __launch_bounds__(kThreads) void kl_partial_kernel(
    const float* __restrict__ score,
    const float* __restrict__ logits,
    float* __restrict__ partial) {

    __shared__ float4 slog4[kTileVec4];          // 40 KB, 16B-aligned by type

    const int t = threadIdx.x;
    const int tile_quad0 = blockIdx.x * kQuadsPerTile;

    // --- coalesced staging: 2560 float4s, 10 per thread, linear ---
    const float4* gsrc = reinterpret_cast<const float4*>(logits + (size_t)tile_quad0 * 20);
    #pragma unroll
    for (int j = 0; j < 10; ++j) {
        const int idx = t + kThreads * j;
        slog4[idx] = gsrc[idx];
    }

    // scores for this thread's 2 quads (coalesced float4 loads)
    const float4* gsc = reinterpret_cast<const float4*>(score + (size_t)tile_quad0 * 4);
    const float4 sA = gsc[t];
    const float4 sB = gsc[t + kThreads];

    __syncthreads();

    // quad t: float4s [5t, 5t+5)   — banks (20t+4j)%32, conflict-free per 8 lanes
    const int a0 = t * 5, b0 = (t + kThreads) * 5;
    float acc = kl_quad(slog4[a0], slog4[a0 + 1], slog4[a0 + 2], slog4[a0 + 3], slog4[a0 + 4], sA)
              + kl_quad(slog4[b0], slog4[b0 + 1], slog4[b0 + 2], slog4[b0 + 3], slog4[b0 + 4], sB);

    // --- wave (64-lane) shuffle reduction ---
    #pragma unroll
    for (int off = 32; off > 0; off >>= 1) acc += __shfl_down(acc, off, 64);

    __shared__ float wsum[4];
    const int lane = t & 63;
    const int wave = t >> 6;
    if (lane == 0) wsum[wave] = acc;
    __syncthreads();
    if (t == 0) {
        partial[blockIdx.x] = wsum[0] + wsum[1] + wsum[2] + wsum[3];
    }
}

__global__ __launch_bounds__(256) void kl_final_kernel(
    const float* __restrict__ partial,
    float* __restrict__ out) {
    const int t = threadIdx.x;
    // 2048 partials = 512 float4s; thread t sums float4 t and t+256
    const float4* p4 = reinterpret_cast<const float4*>(partial);
    const float4 a = p4[t], b = p4[t + 256];
    float acc = a.x + a.y + a.z + a.w + b.x + b.y + b.z + b.w;

    #pragma unroll
    for (int off = 32; off > 0; off >>= 1) acc += __shfl_down(acc, off, 64);

    __shared__ float wsum[4];
    if ((t & 63) == 0) wsum[t >> 6] = acc;
    __syncthreads();
    if (t == 0) {
        out[0] = (wsum[0] + wsum[1] + wsum[2] + wsum[3]) * (9.0f / (float)kBatch);
    }
}

extern "C" void kernel_launch(void* const* d_in, const int* in_sizes, int n_in,
                              void* d_out, int out_size, void* d_ws, size_t ws_size,
                              hipStream_t stream) {
    const float* score  = (const float*)d_in[0];   // quality_score [B]
    const float* logits = (const float*)d_in[1];   // class_logits [B,5]
    float* out     = (float*)d_out;
    float* partial = (float*)d_ws;                 // kBlocks floats, rewritten every call

    kl_partial_kernel<<<kBlocks, kThreads, 0, stream>>>(score, logits, partial);
    kl_final_kernel<<<1, 256, 0, stream>>>(partial, out);
}

// Round 6
// 134.035 us; speedup vs baseline: 1.2224x; 1.0140x over previous
//
#include <hip/hip_runtime.h>
#include <math.h>

// ConsistencyLoss: KL( softmax(soft/T) || softmax(logits/T) ) * T^2, batchmean.
// B = 4,194,304, C = 5, T = 3.
//
// R6: attack staging latency. R5: 40KB LDS @ 256 thr = 16 waves/CU (50%).
// Now: 512 thr/block (1 quad each, same 40KB tile) -> 32 waves/CU (100%),
// and logits staged via __builtin_amdgcn_global_load_lds width=16 (direct
// HBM->LDS DMA, no VGPR round-trip; layout is wave-uniform base + lane*16
// as required). Partials to d_ws + tiny final reduce (no atomic tail).

constexpr int   kC     = 5;
constexpr float kInvT  = 1.0f / 3.0f;
constexpr float kExp13 = 1.3956124250860895f;   // e^{1/3}
constexpr int   kBatch = 4194304;

constexpr int kThreads      = 512;                          // 8 waves
constexpr int kQuadsPerTile = 512;                          // 2048 samples/block
constexpr int kTileVec4     = kQuadsPerTile * 5;            // 2560 float4 = 40 KB
constexpr int kBlocks       = (kBatch / 4) / kQuadsPerTile; // 2048

__device__ __forceinline__ float kl_quad(float4 P0, float4 P1, float4 P2,
                                         float4 P3, float4 P4, float4 s4) {
    const float v[20] = {P0.x, P0.y, P0.z, P0.w,
                         P1.x, P1.y, P1.z, P1.w,
                         P2.x, P2.y, P2.z, P2.w,
                         P3.x, P3.y, P3.z, P3.w,
                         P4.x, P4.y, P4.z, P4.w};
    const float ss[4] = {s4.x, s4.y, s4.z, s4.w};

    float acc = 0.0f;
    #pragma unroll
    for (int r = 0; r < 4; ++r) {
        const float s  = ss[r];
        const float l0 = v[r * 5 + 0], l1 = v[r * 5 + 1], l2 = v[r * 5 + 2],
                    l3 = v[r * 5 + 3], l4 = v[r * 5 + 4];

        // --- soft target geometry (matches reference exactly) ---
        const float sc     = fminf(fmaxf(s * 5.0f, 0.0f), 4.0f);
        const int   idx    = (int)sc;                    // floor, s >= 0
        const float center = ((float)idx + 0.5f) * 0.2f;
        float       d      = fabsf(s - center) * 5.0f;
        const bool  lo     = (idx > 0) && (s < center);
        const bool  hi     = (idx < kC - 1) && (s > center);
        const bool  nb     = lo || hi;
        d = nb ? d : 0.0f;
        const int nbi = idx + (hi ? 1 : 0) - (lo ? 1 : 0);

        // soft = {1-d at idx, d at nbi, 0 elsewhere};  e_main = e^{1/3}/e_nb
        const float e_nb   = __expf(d * kInvT);
        const float e_main = kExp13 * __builtin_amdgcn_rcpf(e_nb);

        const float S = l0 + l1 + l2 + l3 + l4;
        const float l_main = (idx == 0) ? l0 : (idx == 1) ? l1 :
                             (idx == 2) ? l2 : (idx == 3) ? l3 : l4;
        const float l_nb   = (nbi == 0) ? l0 : (nbi == 1) ? l1 :
                             (nbi == 2) ? l2 : (nbi == 3) ? l3 : l4;

        const float Zq = __expf(l0 * kInvT) + __expf(l1 * kInvT) +
                         __expf(l2 * kInvT) + __expf(l3 * kInvT) +
                         __expf(l4 * kInvT);

        const float Zp  = e_main + e_nb + 3.0f;
        const float rZp = __builtin_amdgcn_rcpf(Zp);
        const float Spa = e_main * (1.0f - d) + e_nb * d;
        const float Spl = e_main * l_main + e_nb * l_nb + (S - l_main - l_nb);

        acc += kInvT * (Spa - Spl) * rZp + __logf(Zq * rZp);
    }
    return acc;
}

__global__ __launch_bounds__(kThreads) void kl_partial_kernel(
    const float* __restrict__ score,
    const float* __restrict__ logits,
    float* __restrict__ partial) {

    __shared__ float4 slog4[kTileVec4];          // 40 KB, 16B-aligned by type

    const int t    = threadIdx.x;
    const int wave = t >> 6;                     // 0..7
    const int lane = t & 63;
    const int tile_quad0 = blockIdx.x * kQuadsPerTile;

    // --- async staging: 2560 float4s, 8 waves x 5 iters x 64 lanes ---
    // wave w owns float4 range [w*320, (w+1)*320); iter j is a contiguous
    // 64-float4 (1 KB) chunk: LDS dst = uniform base + lane*16 (HW pattern).
    const float4* gsrc = reinterpret_cast<const float4*>(logits + (size_t)tile_quad0 * 20);
    #pragma unroll
    for (int j = 0; j < 5; ++j) {
        const int base = wave * 320 + j * 64;
        __builtin_amdgcn_global_load_lds(
            (const __attribute__((address_space(1))) void*)(gsrc + base + lane),
            (__attribute__((address_space(3))) void*)(&slog4[base]),
            16, 0, 0);
    }

    // score for this thread's quad (coalesced float4 load, overlaps DMA)
    const float4* gsc = reinterpret_cast<const float4*>(score + (size_t)tile_quad0 * 4);
    const float4 sA = gsc[t];

    __syncthreads();   // drains vmcnt (global_load_lds) for all waves

    // quad t: float4s [5t, 5t+5) — start bank (20t+4j)%32; each 8-lane group
    // covers all 32 banks once per phase -> conflict-free b128 reads.
    const int a0 = t * 5;
    float acc = kl_quad(slog4[a0], slog4[a0 + 1], slog4[a0 + 2],
                        slog4[a0 + 3], slog4[a0 + 4], sA);

    // --- wave (64-lane) shuffle reduction ---
    #pragma unroll
    for (int off = 32; off > 0; off >>= 1) acc += __shfl_down(acc, off, 64);

    __shared__ float wsum[8];
    if (lane == 0) wsum[wave] = acc;
    __syncthreads();
    if (t == 0) {
        float b = 0.0f;
        #pragma unroll
        for (int w = 0; w < 8; ++w) b += wsum[w];
        partial[blockIdx.x] = b;
    }
}

__global__ __launch_bounds__(256) void kl_final_kernel(
    const float* __restrict__ partial,
    float* __restrict__ out) {
    const int t = threadIdx.x;
    // 2048 partials = 512 float4s; thread t sums float4 t and t+256
    const float4* p4 = reinterpret_cast<const float4*>(partial);
    const float4 a = p4[t], b = p4[t + 256];
    float acc = a.x + a.y + a.z + a.w + b.x + b.y + b.z + b.w;

    #pragma unroll
    for (int off = 32; off > 0; off >>= 1) acc += __shfl_down(acc, off, 64);

    __shared__ float wsum[4];
    if ((t & 63) == 0) wsum[t >> 6] = acc;
    __syncthreads();
    if (t == 0) {
        out[0] = (wsum[0] + wsum[1] + wsum[2] + wsum[3]) * (9.0f / (float)kBatch);
    }
}

extern "C" void kernel_launch(void* const* d_in, const int* in_sizes, int n_in,
                              void* d_out, int out_size, void* d_ws, size_t ws_size,
                              hipStream_t stream) {
    const float* score  = (const float*)d_in[0];   // quality_score [B]
    const float* logits = (const float*)d_in[1];   // class_logits [B,5]
    float* out     = (float*)d_out;
    float* partial = (float*)d_ws;                 // kBlocks floats, rewritten every call

    kl_partial_kernel<<<kBlocks, kThreads, 0, stream>>>(score, logits, partial);
    kl_final_kernel<<<1, 256, 0, stream>>>(partial, out);
}